// Round 2
// baseline (2354.322 us; speedup 1.0000x reference)
//
#include <hip/hip_runtime.h>
#include <math.h>

#define HW 9216
#define CIN 256
#define COUT 256

struct F2 { float a, b; };

// ---------------- K1: offsets conv 256->18, 3x3, pad 1 ----------------
// 8x8 pixel tile, 4-way cin split (cpart = t>>6), LDS reduce. 576 blocks.
__global__ __launch_bounds__(256) void k_off(const float* __restrict__ x,
                                             const float* __restrict__ w_off,
                                             const float* __restrict__ b_off,
                                             float* __restrict__ off) {
    __shared__ float red[4][64][19];   // padded 18->19: odd stride, conflict-free
    int t = threadIdx.x;
    int px = t & 63, cpart = t >> 6;
    int lh = px >> 3, lw = px & 7;
    int h = blockIdx.y * 8 + lh, w = blockIdx.x * 8 + lw;
    int b = blockIdx.z;

    float acc[18];
#pragma unroll
    for (int o = 0; o < 18; ++o) acc[o] = 0.f;

    const float* xb = x + (size_t)b * CIN * HW;
    for (int ci = 0; ci < 64; ++ci) {
        int c = cpart * 64 + ci;                    // wave-uniform cpart
        const float* xp = xb + (size_t)c * HW;
        float xr[9];
#pragma unroll
        for (int dy = -1; dy <= 1; ++dy)
#pragma unroll
            for (int dx = -1; dx <= 1; ++dx) {
                int hh = h + dy, ww = w + dx;
                bool ok = ((unsigned)hh < 96u) && ((unsigned)ww < 96u);
                xr[(dy + 1) * 3 + dx + 1] = ok ? xp[hh * 96 + ww] : 0.f;
            }
        const float* wp = w_off + (size_t)c * 9;
#pragma unroll
        for (int o = 0; o < 18; ++o) {
            const float* wo = wp + (size_t)o * CIN * 9;   // wave-uniform -> s_load
            float s = 0.f;
#pragma unroll
            for (int k = 0; k < 9; ++k) s += xr[k] * wo[k];
            acc[o] += s;
        }
    }
#pragma unroll
    for (int o = 0; o < 18; ++o) red[cpart][px][o] = acc[o];
    __syncthreads();
    if (t < 64) {
        int hh = blockIdx.y * 8 + (t >> 3), ww = blockIdx.x * 8 + (t & 7);
#pragma unroll
        for (int o = 0; o < 18; ++o) {
            float s = red[0][t][o] + red[1][t][o] + red[2][t][o] + red[3][t][o]
                    + b_off[o];
            off[((size_t)(b * 18 + o)) * HW + hh * 96 + ww] = s;
        }
    }
}

// ---------------- K2: deformable conv as implicit GEMM ----------------
// Tile: 64 pixels (8x8) x 256 couts, 256 threads, K=2304 chunked 16 cin.
// LDS: s_lds 36KB + idx 4.5KB + wt 9KB = 49.5KB -> 3 blocks/CU.
__global__ __launch_bounds__(256, 3) void k_dcn(const float* __restrict__ x,
                                                const float* __restrict__ off,
                                                const float* __restrict__ w_dcn,
                                                const float* __restrict__ b_dcn,
                                                float* __restrict__ y,
                                                float* __restrict__ gsum,
                                                float* __restrict__ gss) {
    __shared__ float  s_lds[64 * 144];   // [pixel][cl*9+k]
    __shared__ short4 idx_s[64 * 9];     // bilinear corner indices per (pixel, tap)
    __shared__ float4 wt4_l[64 * 9];     // bilinear corner weights per (pixel, tap)

    int t = threadIdx.x;
    int b = blockIdx.z;
    int h0 = blockIdx.y * 8, w0 = blockIdx.x * 8;

    // ---- Phase A: bilinear indices/weights per (pixel, tap): 576 entries ----
#pragma unroll
    for (int it = 0; it < 3; ++it) {
        int e = t + it * 256;
        if (e < 576) {
            int p = e / 9, k = e - p * 9;
            int h = h0 + (p >> 3), w = w0 + (p & 7);
            const float* ob = off + (size_t)b * 18 * HW + h * 96 + w;
            float oy = ob[(size_t)(2 * k) * HW];
            float ox = ob[(size_t)(2 * k + 1) * HW];
            float py = (float)(h + k / 3 - 1) + oy;
            float px = (float)(w + k % 3 - 1) + ox;
            float y0f = floorf(py), x0f = floorf(px);
            float wy = py - y0f, wx = px - x0f;
            int yi0 = (int)y0f, xi0 = (int)x0f;
            int yi1 = yi0 + 1, xi1 = xi0 + 1;
            bool vy0 = (unsigned)yi0 < 96u, vy1 = (unsigned)yi1 < 96u;
            bool vx0 = (unsigned)xi0 < 96u, vx1 = (unsigned)xi1 < 96u;
            int cy0 = min(max(yi0, 0), 95), cy1 = min(max(yi1, 0), 95);
            int cx0 = min(max(xi0, 0), 95), cx1 = min(max(xi1, 0), 95);
            idx_s[e] = make_short4((short)(cy0 * 96 + cx0), (short)(cy0 * 96 + cx1),
                                   (short)(cy1 * 96 + cx0), (short)(cy1 * 96 + cx1));
            wt4_l[e] = make_float4((vy0 && vx0) ? (1.f - wy) * (1.f - wx) : 0.f,
                                   (vy0 && vx1) ? (1.f - wy) * wx : 0.f,
                                   (vy1 && vx0) ? wy * (1.f - wx) : 0.f,
                                   (vy1 && vx1) ? wy * wx : 0.f);
        }
    }
    __syncthreads();

    int g  = t & 31;       // cout octet == groupnorm group id
    int pg = t >> 5;       // pixel octet
    int c0 = g * 8;
    int p0 = pg * 8;
    float acc[8][8] = {};

    const float* xb = x + (size_t)b * CIN * HW;
    int sp  = t >> 2;           // sampling pixel for this thread
    int sub = t & 3;            // cin sub-slot

    for (int cc = 0; cc < 16; ++cc) {
        const float* xchunk = xb + (size_t)cc * 16 * HW;
        // ---- sample: thread t fills pixel sp, cins sub*4..sub*4+3, all 9 taps ----
#pragma unroll
        for (int k = 0; k < 9; ++k) {
            short4 id = idx_s[sp * 9 + k];
            float4 wt = wt4_l[sp * 9 + k];
#pragma unroll
            for (int ci = 0; ci < 4; ++ci) {
                int cl = sub * 4 + ci;
                const float* xp = xchunk + (size_t)cl * HW;
                s_lds[sp * 144 + cl * 9 + k] =
                    xp[id.x] * wt.x + xp[id.y] * wt.y +
                    xp[id.z] * wt.z + xp[id.w] * wt.w;
            }
        }
        __syncthreads();

        // ---- GEMM: 8px x 8cout x 144k per thread ----
        const float* wbase = w_dcn + cc * 144;
        for (int kk = 0; kk < 144; kk += 4) {
            float4 sv[8];
#pragma unroll
            for (int i = 0; i < 8; ++i)
                sv[i] = *(const float4*)&s_lds[(p0 + i) * 144 + kk];
#pragma unroll
            for (int j = 0; j < 8; ++j) {
                float4 wv = *(const float4*)(wbase + (size_t)(c0 + j) * 2304 + kk);
#pragma unroll
                for (int i = 0; i < 8; ++i)
                    acc[i][j] += sv[i].x * wv.x + sv[i].y * wv.y +
                                 sv[i].z * wv.z + sv[i].w * wv.w;
            }
        }
        __syncthreads();
    }

    // ---- epilogue: bias, store y, groupnorm partials ----
    float psum = 0.f, pss = 0.f;
#pragma unroll
    for (int i = 0; i < 8; ++i) {
        int p = p0 + i;
        int h = h0 + (p >> 3), w = w0 + (p & 7);
#pragma unroll
        for (int j = 0; j < 8; ++j) {
            int c = c0 + j;
            float v = acc[i][j] + b_dcn[c];
            y[((size_t)(b * COUT + c)) * HW + h * 96 + w] = v;
            psum += v;
            pss += v * v;
        }
    }
    float* red = s_lds;            // s_lds dead after last barrier -> reuse
    red[t] = psum;
    red[256 + t] = pss;
    __syncthreads();
    if (t < 32) {
        float s = 0.f, ss = 0.f;
#pragma unroll
        for (int j = 0; j < 8; ++j) {
            s  += red[t + 32 * j];
            ss += red[256 + t + 32 * j];
        }
        int blk = blockIdx.y * 12 + blockIdx.x;  // 0..143
        gsum[((size_t)(b * 32 + t)) * 144 + blk] = s;
        gss [((size_t)(b * 32 + t)) * 144 + blk] = ss;
    }
}

// ---------------- K3: finish groupnorm stats -> per (b,c) scale/shift ----------------
__global__ void k_stats(const float* __restrict__ gsum, const float* __restrict__ gss,
                        const float* __restrict__ gamma, const float* __restrict__ beta,
                        F2* __restrict__ ab) {
    int t = blockIdx.x * 256 + threadIdx.x;  // 0..1023 = b*256+c
    if (t >= 1024) return;
    int b = t >> 8, c = t & 255, g = c >> 3;
    const float* ps = gsum + (size_t)(b * 32 + g) * 144;
    const float* pq = gss  + (size_t)(b * 32 + g) * 144;
    float s = 0.f, q = 0.f;
    for (int i = 0; i < 144; ++i) { s += ps[i]; q += pq[i]; }
    const float inv_n = 1.f / 73728.f;
    float mu = s * inv_n;
    float var = q * inv_n - mu * mu;
    float rstd = rsqrtf(var + 1e-5f);
    float A = rstd * gamma[c];
    float Bv = beta[c] - mu * A;
    ab[t].a = A;
    ab[t].b = Bv;
}

// ---------------- K4: sigmoid gate field (256->1 conv on normalized y) ----------------
// 8x8 pixel tile, 4-way c split, LDS reduce. 576 blocks.
__global__ __launch_bounds__(256) void k_sig(const float* __restrict__ y,
                                             const F2* __restrict__ ab,
                                             const float* __restrict__ w2,
                                             const float* __restrict__ b2,
                                             float* __restrict__ sig) {
    __shared__ float red[4][64];
    int t = threadIdx.x;
    int px = t & 63, cpart = t >> 6;
    int lh = px >> 3, lw = px & 7;
    int h = blockIdx.y * 8 + lh, w = blockIdx.x * 8 + lw;
    int b = blockIdx.z;

    float acc = 0.f;
    for (int ci = 0; ci < 64; ++ci) {
        int c = cpart * 64 + ci;                 // wave-uniform
        const float* yp = y + ((size_t)(b * 256 + c)) * HW;
        F2 p = ab[b * 256 + c];
        const float* wp = w2 + (size_t)c * 9;
#pragma unroll
        for (int dy = -1; dy <= 1; ++dy)
#pragma unroll
            for (int dx = -1; dx <= 1; ++dx) {
                int hh = h + dy, ww = w + dx;
                bool ok = ((unsigned)hh < 96u) && ((unsigned)ww < 96u);
                float x1 = ok ? yp[hh * 96 + ww] * p.a + p.b : 0.f;  // zero-pad x1
                acc += x1 * wp[(dy + 1) * 3 + dx + 1];
            }
    }
    red[cpart][px] = acc;
    __syncthreads();
    if (t < 64) {
        float s = red[0][t] + red[1][t] + red[2][t] + red[3][t] + b2[0];
        int hh = blockIdx.y * 8 + (t >> 3), ww = blockIdx.x * 8 + (t & 7);
        sig[(size_t)b * HW + hh * 96 + ww] = 1.f / (1.f + expf(-s));
    }
}

// ---------------- K5: out = x1 * sig ----------------
__global__ __launch_bounds__(256) void k_final(const float* __restrict__ y,
                                               const F2* __restrict__ ab,
                                               const float* __restrict__ sig,
                                               float* __restrict__ out, int n4) {
    int i = blockIdx.x * 256 + threadIdx.x;
    if (i >= n4) return;
    float4 yv = ((const float4*)y)[i];
    int plane = (i * 4) / HW;           // b*256+c  (HW divisible by 4)
    int sp = i * 4 - plane * HW;
    F2 p = ab[plane];
    int b = plane >> 8;
    const float4 sv = *(const float4*)(sig + (size_t)b * HW + sp);
    float4 o;
    o.x = (yv.x * p.a + p.b) * sv.x;
    o.y = (yv.y * p.a + p.b) * sv.y;
    o.z = (yv.z * p.a + p.b) * sv.z;
    o.w = (yv.w * p.a + p.b) * sv.w;
    ((float4*)out)[i] = o;
}

extern "C" void kernel_launch(void* const* d_in, const int* in_sizes, int n_in,
                              void* d_out, int out_size, void* d_ws, size_t ws_size,
                              hipStream_t stream) {
    const float* x     = (const float*)d_in[0];
    const float* w_off = (const float*)d_in[1];
    const float* b_off = (const float*)d_in[2];
    const float* w_dcn = (const float*)d_in[3];
    const float* b_dcn = (const float*)d_in[4];
    const float* gamma = (const float*)d_in[5];
    const float* beta  = (const float*)d_in[6];
    const float* w2    = (const float*)d_in[7];
    const float* b2    = (const float*)d_in[8];
    float* out = (float*)d_out;

    float* ws   = (float*)d_ws;
    float* off  = ws;                    // 4*18*9216    = 663552 floats
    float* y    = off + 663552;          // 4*256*9216   = 9437184
    float* gsum = y + 9437184;           // 4*32*144     = 18432
    float* gss  = gsum + 18432;          // 18432
    F2*    ab   = (F2*)(gss + 18432);    // 1024 F2
    float* sig  = (float*)(ab + 1024);   // 4*9216       = 36864

    k_off  <<<dim3(12, 12, 4), 256, 0, stream>>>(x, w_off, b_off, off);
    k_dcn  <<<dim3(12, 12, 4), 256, 0, stream>>>(x, off, w_dcn, b_dcn, y, gsum, gss);
    k_stats<<<4,               256, 0, stream>>>(gsum, gss, gamma, beta, ab);
    k_sig  <<<dim3(12, 12, 4), 256, 0, stream>>>(y, ab, w2, b2, sig);
    k_final<<<9216,            256, 0, stream>>>(y, ab, sig, out, 2359296);
}

// Round 3
// 792.066 us; speedup vs baseline: 2.9724x; 2.9724x over previous
//
#include <hip/hip_runtime.h>
#include <math.h>

#define HW 9216
#define CIN 256
#define COUT 256

typedef _Float16 f16;
typedef _Float16 half8 __attribute__((ext_vector_type(8)));
typedef float f32x4 __attribute__((ext_vector_type(4)));

struct F2 { float a, b; };

// ---------------- K0a: x NCHW f32 -> xt NHWC f16 ----------------
__global__ __launch_bounds__(256) void k_prep_x(const float* __restrict__ x,
                                                f16* __restrict__ xt) {
    __shared__ f16 tile[64][256];
    int bx = blockIdx.x;
    int b = bx / 144, pxb = (bx % 144) * 64;
    int t = threadIdx.x;
    int cq = t >> 2, q = t & 3;
    for (int cp = 0; cp < 4; ++cp) {
        int c = cp * 64 + cq;
        const float* src = x + ((size_t)(b * 256 + c)) * HW + pxb + q * 16;
#pragma unroll
        for (int ii = 0; ii < 4; ++ii) {
            float4 v = *(const float4*)(src + ii * 4);
            int p0 = q * 16 + ii * 4;
            tile[p0 + 0][c] = (f16)v.x; tile[p0 + 1][c] = (f16)v.y;
            tile[p0 + 2][c] = (f16)v.z; tile[p0 + 3][c] = (f16)v.w;
        }
    }
    __syncthreads();
    int cg = t & 31, ph = t >> 5;
#pragma unroll
    for (int it = 0; it < 8; ++it) {
        int px = it * 8 + ph;
        *(uint4*)(xt + ((size_t)(b * HW + pxb + px)) * 256 + cg * 8) =
            *(const uint4*)&tile[px][cg * 8];
    }
}

// ---------------- K0b: w_dcn [cout][cin][9] f32 -> wt f16, tap-major, frag-permuted ----
// stored[cout][b32*32 + g*8 + h*4 + j] = w_dcn[cout][cin][tap],  kk=b32*32+h*16+g*4+j,
// tap=kk>>8, cin=kk&255.  (fragment: elems 0-3 -> k=(lane>>4)*4+j, elems 4-7 -> +16)
__global__ __launch_bounds__(256) void k_prep_w(const float* __restrict__ w_dcn,
                                                f16* __restrict__ wt) {
    int gid = blockIdx.x * 256 + threadIdx.x;   // < 589824
    int cout = gid / 2304, pos = gid - cout * 2304;
    int b32 = pos >> 5, qq = pos & 31;
    int gg = qq >> 3, hh = (qq >> 2) & 1, jj = qq & 3;
    int kk = b32 * 32 + hh * 16 + gg * 4 + jj;
    int tap = kk >> 8, cin = kk & 255;
    wt[gid] = (f16)w_dcn[((size_t)cout * 256 + cin) * 9 + tap];
}

// ---------------- K1: offsets conv 256->18 (fp32 VALU, proven path; f16 store) ----
__global__ __launch_bounds__(256) void k_off(const float* __restrict__ x,
                                             const float* __restrict__ w_off,
                                             const float* __restrict__ b_off,
                                             f16* __restrict__ off) {
    __shared__ float red[4][64][19];
    int t = threadIdx.x;
    int px = t & 63, cpart = t >> 6;
    int lh = px >> 3, lw = px & 7;
    int h = blockIdx.y * 8 + lh, w = blockIdx.x * 8 + lw;
    int b = blockIdx.z;

    float acc[18];
#pragma unroll
    for (int o = 0; o < 18; ++o) acc[o] = 0.f;

    const float* xb = x + (size_t)b * CIN * HW;
    for (int ci = 0; ci < 64; ++ci) {
        int c = cpart * 64 + ci;
        const float* xp = xb + (size_t)c * HW;
        float xr[9];
#pragma unroll
        for (int dy = -1; dy <= 1; ++dy)
#pragma unroll
            for (int dx = -1; dx <= 1; ++dx) {
                int hh = h + dy, ww = w + dx;
                bool ok = ((unsigned)hh < 96u) && ((unsigned)ww < 96u);
                xr[(dy + 1) * 3 + dx + 1] = ok ? xp[hh * 96 + ww] : 0.f;
            }
        const float* wp = w_off + (size_t)c * 9;
#pragma unroll
        for (int o = 0; o < 18; ++o) {
            const float* wo = wp + (size_t)o * CIN * 9;
            float s = 0.f;
#pragma unroll
            for (int k = 0; k < 9; ++k) s += xr[k] * wo[k];
            acc[o] += s;
        }
    }
#pragma unroll
    for (int o = 0; o < 18; ++o) red[cpart][px][o] = acc[o];
    __syncthreads();
    if (t < 64) {
        int hh = blockIdx.y * 8 + (t >> 3), ww = blockIdx.x * 8 + (t & 7);
#pragma unroll
        for (int o = 0; o < 18; ++o) {
            float s = red[0][t][o] + red[1][t][o] + red[2][t][o] + red[3][t][o]
                    + b_off[o];
            off[((size_t)(b * 18 + o)) * HW + hh * 96 + ww] = (f16)s;
        }
    }
}

// ---------------- K2: deformable conv, fp16 MFMA implicit GEMM ----------------
// Block: 64 px x 128 cout (ch half), 256 thr = 4 waves; wave: 4 px-rows x 2 cout-cols.
// K = 9 taps x 8 K-steps(32 cin).  A: sampled f16 in swizzled LDS; B: wt f16 global.
__global__ __launch_bounds__(256, 2) void k_dcn(const f16* __restrict__ xt,
                                                const f16* __restrict__ off,
                                                const f16* __restrict__ wt,
                                                const float* __restrict__ b_dcn,
                                                f16* __restrict__ y,
                                                float* __restrict__ gsum,
                                                float* __restrict__ gss) {
    __shared__ uint4  A4[2048];     // 32KB  A_lds[64px][256cin] f16, frag-permuted+XOR-swizzled
    __shared__ int4   idx4[576];    // [tap][px] corner BYTE offsets into xt batch
    __shared__ float4 wt4[576];     // [tap][px] bilinear corner weights

    int bx = blockIdx.x;
    int tile = bx % 144;
    int ch = (bx / 144) & 1;
    int b = bx / 288;
    int pxb = tile * 64;
    int t = threadIdx.x;

    // ---- Phase A: bilinear tables (576 = 9 taps x 64 px) ----
    for (int e = t; e < 576; e += 256) {
        int p = e & 63, tap = e >> 6;
        int pxf = pxb + p;
        int h = pxf / 96, w = pxf - h * 96;
        const f16* ob = off + (size_t)b * 18 * HW + pxf;
        float oy = (float)ob[(size_t)(2 * tap) * HW];
        float ox = (float)ob[(size_t)(2 * tap + 1) * HW];
        float py  = (float)(h + tap / 3 - 1) + oy;
        float pxx = (float)(w + tap % 3 - 1) + ox;
        float y0f = floorf(py), x0f = floorf(pxx);
        float wy = py - y0f, wx = pxx - x0f;
        int yi0 = (int)y0f, xi0 = (int)x0f;
        int yi1 = yi0 + 1, xi1 = xi0 + 1;
        bool vy0 = (unsigned)yi0 < 96u, vy1 = (unsigned)yi1 < 96u;
        bool vx0 = (unsigned)xi0 < 96u, vx1 = (unsigned)xi1 < 96u;
        int cy0 = min(max(yi0, 0), 95), cy1 = min(max(yi1, 0), 95);
        int cx0 = min(max(xi0, 0), 95), cx1 = min(max(xi1, 0), 95);
        idx4[e] = make_int4((cy0 * 96 + cx0) * 512, (cy0 * 96 + cx1) * 512,
                            (cy1 * 96 + cx0) * 512, (cy1 * 96 + cx1) * 512);
        wt4[e] = make_float4((vy0 && vx0) ? (1.f - wy) * (1.f - wx) : 0.f,
                             (vy0 && vx1) ? (1.f - wy) * wx : 0.f,
                             (vy1 && vx0) ? wy * (1.f - wx) : 0.f,
                             (vy1 && vx1) ? wy * wx : 0.f);
    }

    int lane = t & 63, wv = t >> 6;
    int g = lane >> 4, l15 = lane & 15;
    const char* xtb = (const char*)(xt + (size_t)b * HW * 256);

    f32x4 acc[4][2];
#pragma unroll
    for (int R = 0; R < 4; ++R) {
        acc[R][0] = (f32x4){0.f, 0.f, 0.f, 0.f};
        acc[R][1] = (f32x4){0.f, 0.f, 0.f, 0.f};
    }

    int sp = t & 63, c64 = t >> 6;   // sampler: pixel sp, cins [c64*64, +64)
    int cout0 = ch * 128 + wv * 32 + l15;
    const f16* wrow = wt + (size_t)cout0 * 2304;

    for (int tap = 0; tap < 9; ++tap) {
        __syncthreads();   // A4 free (covers Phase A on first iter)
        int4   id  = idx4[tap * 64 + sp];
        float4 wgt = wt4[tap * 64 + sp];
        const char* p0 = xtb + id.x;
        const char* p1 = xtb + id.y;
        const char* p2 = xtb + id.z;
        const char* p3 = xtb + id.w;
#pragma unroll
        for (int gi = 0; gi < 8; ++gi) {
            int cb = c64 * 128 + gi * 16;
            uint4 q0 = *(const uint4*)(p0 + cb);
            uint4 q1 = *(const uint4*)(p1 + cb);
            uint4 q2 = *(const uint4*)(p2 + cb);
            uint4 q3 = *(const uint4*)(p3 + cb);
            const f16* a0 = (const f16*)&q0;
            const f16* a1 = (const f16*)&q1;
            const f16* a2 = (const f16*)&q2;
            const f16* a3 = (const f16*)&q3;
            union { f16 h[8]; uint2 u2[2]; } pu;
#pragma unroll
            for (int ii = 0; ii < 8; ++ii) {
                float s = wgt.x * (float)a0[ii] + wgt.y * (float)a1[ii]
                        + wgt.z * (float)a2[ii] + wgt.w * (float)a3[ii];
                pu.h[ii] = (f16)s;
            }
            // permuted write: natural 8-cin group -> two 8B slot runs
            int kb = c64 * 2 + (gi >> 2);
            int ra = (gi & 1) * 32 + ((gi & 2) ? 8 : 0);
            int preA = sp * 512 + kb * 64 + ra;
            int swz = (sp & 7) << 4;
            *(uint2*)((char*)A4 + ((preA) ^ swz))      = pu.u2[0];
            *(uint2*)((char*)A4 + ((preA + 16) ^ swz)) = pu.u2[1];
        }
        __syncthreads();

        // ---- MFMA: 8 K-steps of 32 ----
#pragma unroll
        for (int kb = 0; kb < 8; ++kb) {
            half8 Af[4];
#pragma unroll
            for (int R = 0; R < 4; ++R) {
                int byteA = ((R * 16 + l15) * 512 + kb * 64 + g * 16) ^ ((l15 & 7) << 4);
                Af[R] = *(const half8*)((const char*)A4 + byteA);
            }
#pragma unroll
            for (int nc = 0; nc < 2; ++nc) {
                half8 Bf = *(const half8*)(wrow + nc * 16 * 2304 + tap * 256 + kb * 32 + g * 8);
#pragma unroll
                for (int R = 0; R < 4; ++R)
                    acc[R][nc] = __builtin_amdgcn_mfma_f32_16x16x32_f16(Af[R], Bf, acc[R][nc], 0, 0, 0);
            }
        }
    }

    // ---- epilogue: bias, y f16 store, groupnorm partials ----
    float bias[2] = { b_dcn[cout0], b_dcn[cout0 + 16] };
    float psum[2] = {0.f, 0.f}, pss[2] = {0.f, 0.f};
#pragma unroll
    for (int R = 0; R < 4; ++R)
#pragma unroll
        for (int nc = 0; nc < 2; ++nc) {
            f32x4 v = acc[R][nc];
            v.x += bias[nc]; v.y += bias[nc]; v.z += bias[nc]; v.w += bias[nc];
            int cout = cout0 + nc * 16;
            union { f16 h[4]; uint2 u; } pk;
            pk.h[0] = (f16)v.x; pk.h[1] = (f16)v.y; pk.h[2] = (f16)v.z; pk.h[3] = (f16)v.w;
            *(uint2*)(y + ((size_t)(b * 256 + cout)) * HW + pxb + R * 16 + g * 4) = pk.u;
            psum[nc] += v.x + v.y + v.z + v.w;
            pss[nc]  += v.x * v.x + v.y * v.y + v.z * v.z + v.w * v.w;
        }
    __syncthreads();
    float4* red = (float4*)A4;
    red[t] = make_float4(psum[0], pss[0], psum[1], pss[1]);
    __syncthreads();
    if (t < 16) {
        int w_ = t >> 2, nc = (t >> 1) & 1, h8 = t & 1;
        float s = 0.f, ss = 0.f;
        for (int g2 = 0; g2 < 4; ++g2)
            for (int i = 0; i < 8; ++i) {
                float4 r = red[w_ * 64 + g2 * 16 + h8 * 8 + i];
                s  += nc ? r.z : r.x;
                ss += nc ? r.w : r.y;
            }
        int G = ch * 16 + w_ * 4 + nc * 2 + h8;
        gsum[((size_t)(b * 32 + G)) * 144 + tile] = s;
        gss [((size_t)(b * 32 + G)) * 144 + tile] = ss;
    }
}

// ---------------- K3: finish groupnorm stats ----------------
__global__ void k_stats(const float* __restrict__ gsum, const float* __restrict__ gss,
                        const float* __restrict__ gamma, const float* __restrict__ beta,
                        F2* __restrict__ ab) {
    int t = blockIdx.x * 256 + threadIdx.x;
    if (t >= 1024) return;
    int b = t >> 8, c = t & 255, g = c >> 3;
    const float* ps = gsum + (size_t)(b * 32 + g) * 144;
    const float* pq = gss  + (size_t)(b * 32 + g) * 144;
    float s = 0.f, q = 0.f;
    for (int i = 0; i < 144; ++i) { s += ps[i]; q += pq[i]; }
    const float inv_n = 1.f / 73728.f;
    float mu = s * inv_n;
    float var = q * inv_n - mu * mu;
    float rstd = rsqrtf(var + 1e-5f);
    float A = rstd * gamma[c];
    float Bv = beta[c] - mu * A;
    ab[t].a = A;
    ab[t].b = Bv;
}

// ---------------- K4: sigmoid gate (256->1 conv on normalized y) ----------------
__global__ __launch_bounds__(256) void k_sig(const f16* __restrict__ y,
                                             const F2* __restrict__ ab,
                                             const float* __restrict__ w2,
                                             const float* __restrict__ b2,
                                             float* __restrict__ sig) {
    __shared__ float red[4][64];
    int t = threadIdx.x;
    int px = t & 63, cpart = t >> 6;
    int lh = px >> 3, lw = px & 7;
    int h = blockIdx.y * 8 + lh, w = blockIdx.x * 8 + lw;
    int b = blockIdx.z;

    float acc = 0.f;
    for (int ci = 0; ci < 64; ++ci) {
        int c = cpart * 64 + ci;
        const f16* yp = y + ((size_t)(b * 256 + c)) * HW;
        F2 p = ab[b * 256 + c];
        const float* wp = w2 + (size_t)c * 9;
#pragma unroll
        for (int dy = -1; dy <= 1; ++dy)
#pragma unroll
            for (int dx = -1; dx <= 1; ++dx) {
                int hh = h + dy, ww = w + dx;
                bool ok = ((unsigned)hh < 96u) && ((unsigned)ww < 96u);
                float x1 = ok ? (float)yp[hh * 96 + ww] * p.a + p.b : 0.f;
                acc += x1 * wp[(dy + 1) * 3 + dx + 1];
            }
    }
    red[cpart][px] = acc;
    __syncthreads();
    if (t < 64) {
        float s = red[0][t] + red[1][t] + red[2][t] + red[3][t] + b2[0];
        int hh = blockIdx.y * 8 + (t >> 3), ww = blockIdx.x * 8 + (t & 7);
        sig[(size_t)b * HW + hh * 96 + ww] = 1.f / (1.f + expf(-s));
    }
}

// ---------------- K5: out = x1 * sig ----------------
__global__ __launch_bounds__(256) void k_final(const f16* __restrict__ y,
                                               const F2* __restrict__ ab,
                                               const float* __restrict__ sig,
                                               float* __restrict__ out, int n8) {
    int i = blockIdx.x * 256 + threadIdx.x;
    if (i >= n8) return;
    uint4 yv = ((const uint4*)y)[i];
    const f16* hp = (const f16*)&yv;
    int plane = (i * 8) / HW;
    int sp = i * 8 - plane * HW;
    F2 p = ab[plane];
    int b = plane >> 8;
    const float* sb = sig + (size_t)b * HW + sp;
    float4 s0 = *(const float4*)sb;
    float4 s1 = *(const float4*)(sb + 4);
    float4 o0, o1;
    o0.x = ((float)hp[0] * p.a + p.b) * s0.x;
    o0.y = ((float)hp[1] * p.a + p.b) * s0.y;
    o0.z = ((float)hp[2] * p.a + p.b) * s0.z;
    o0.w = ((float)hp[3] * p.a + p.b) * s0.w;
    o1.x = ((float)hp[4] * p.a + p.b) * s1.x;
    o1.y = ((float)hp[5] * p.a + p.b) * s1.y;
    o1.z = ((float)hp[6] * p.a + p.b) * s1.z;
    o1.w = ((float)hp[7] * p.a + p.b) * s1.w;
    ((float4*)out)[i * 2]     = o0;
    ((float4*)out)[i * 2 + 1] = o1;
}

extern "C" void kernel_launch(void* const* d_in, const int* in_sizes, int n_in,
                              void* d_out, int out_size, void* d_ws, size_t ws_size,
                              hipStream_t stream) {
    (void)in_sizes; (void)n_in; (void)out_size; (void)ws_size;
    const float* x     = (const float*)d_in[0];
    const float* w_off = (const float*)d_in[1];
    const float* b_off = (const float*)d_in[2];
    const float* w_dcn = (const float*)d_in[3];
    const float* b_dcn = (const float*)d_in[4];
    const float* gamma = (const float*)d_in[5];
    const float* beta  = (const float*)d_in[6];
    const float* w2    = (const float*)d_in[7];
    const float* b2    = (const float*)d_in[8];
    float* out = (float*)d_out;

    char* p = (char*)d_ws;
    f16*   offp = (f16*)p;    p += 1327104;    // 4*18*9216 f16
    f16*   y    = (f16*)p;    p += 18874368;   // 4*256*9216 f16
    float* gsum = (float*)p;  p += 73728;      // 4*32*144 f32
    float* gss  = (float*)p;  p += 73728;
    F2*    ab   = (F2*)p;     p += 8192;       // 1024 F2
    float* sig  = (float*)p;  p += 147456;     // 4*9216 f32
    f16*   xt   = (f16*)p;    p += 18874368;   // 4*9216*256 f16
    f16*   wtp  = (f16*)p;    p += 1179648;    // 256*2304 f16
    // total = 40,558,592 B (< 40.7 MB proven available)

    k_prep_x<<<576,  256, 0, stream>>>(x, xt);
    k_prep_w<<<2304, 256, 0, stream>>>(w_dcn, wtp);
    k_off   <<<dim3(12, 12, 4), 256, 0, stream>>>(x, w_off, b_off, offp);
    k_dcn   <<<1152, 256, 0, stream>>>(xt, offp, wtp, b_dcn, y, gsum, gss);
    k_stats <<<4,    256, 0, stream>>>(gsum, gss, gamma, beta, ab);
    k_sig   <<<dim3(12, 12, 4), 256, 0, stream>>>(y, ab, w2, b2, sig);
    k_final <<<4608, 256, 0, stream>>>(y, ab, sig, out, 1179648);
}

// Round 6
// 528.941 us; speedup vs baseline: 4.4510x; 1.4975x over previous
//
#include <hip/hip_runtime.h>
#include <math.h>

#define HW 9216
#define CIN 256
#define COUT 256

typedef _Float16 f16;
typedef _Float16 half8 __attribute__((ext_vector_type(8)));
typedef float f32x4 __attribute__((ext_vector_type(4)));

struct F2 { float a, b; };

// ---------------- K0a: x NCHW f32 -> xt NHWC f16 (proven r3) ----------------
__global__ __launch_bounds__(256) void k_prep_x(const float* __restrict__ x,
                                                f16* __restrict__ xt) {
    __shared__ f16 tile[64][256];
    int bx = blockIdx.x;
    int b = bx / 144, pxb = (bx % 144) * 64;
    int t = threadIdx.x;
    int cq = t >> 2, q = t & 3;
    for (int cp = 0; cp < 4; ++cp) {
        int c = cp * 64 + cq;
        const float* src = x + ((size_t)(b * 256 + c)) * HW + pxb + q * 16;
#pragma unroll
        for (int ii = 0; ii < 4; ++ii) {
            float4 v = *(const float4*)(src + ii * 4);
            int p0 = q * 16 + ii * 4;
            tile[p0 + 0][c] = (f16)v.x; tile[p0 + 1][c] = (f16)v.y;
            tile[p0 + 2][c] = (f16)v.z; tile[p0 + 3][c] = (f16)v.w;
        }
    }
    __syncthreads();
    int cg = t & 31, ph = t >> 5;
#pragma unroll
    for (int it = 0; it < 8; ++it) {
        int px = it * 8 + ph;
        *(uint4*)(xt + ((size_t)(b * HW + pxb + px)) * 256 + cg * 8) =
            *(const uint4*)&tile[px][cg * 8];
    }
}

// ---------------- K0b: w_dcn -> wt2 f16, coalesced frag-major layout ----------------
// wt2[(((tap*8+kb)*4+g)*256 + cout)*8 + e] = w_dcn[cout][cin][tap],
// cin = kb*32 + (e>>2)*16 + g*4 + (e&3)  (fragment semantics proven in r3)
__global__ __launch_bounds__(256) void k_prep_w(const float* __restrict__ w_dcn,
                                                f16* __restrict__ wt2) {
    int gid = blockIdx.x * 256 + threadIdx.x;   // < 589824
    int e = gid & 7;
    int cout = (gid >> 3) & 255;
    int r2 = gid >> 11;
    int g = r2 & 3, kb = (r2 >> 2) & 7, tap = r2 >> 5;
    int cin = kb * 32 + ((e >> 2) << 4) + (g << 2) + (e & 3);
    wt2[gid] = (f16)w_dcn[((size_t)cout * 256 + cin) * 9 + tap];
}

// ---------------- K0c: w_off [o][cin][tap] -> w_offp [(o*9+tap)*256 + cin] f32 ----
__global__ __launch_bounds__(256) void k_prep_wo(const float* __restrict__ w_off,
                                                 float* __restrict__ w_offp) {
    int gid = blockIdx.x * 256 + threadIdx.x;   // 41472 exact
    int cin = gid & 255;
    int r = gid >> 8;                           // o*9+tap
    int tap = r % 9, o = r / 9;
    w_offp[gid] = w_off[((size_t)o * 256 + cin) * 9 + tap];
}

// ---------------- K1: offsets conv 256->18, reads xt NHWC f16 ----------------
__global__ __launch_bounds__(512) void k_off(const f16* __restrict__ xt,
                                             const float* __restrict__ w_offp,
                                             const float* __restrict__ b_off,
                                             f16* __restrict__ off) {
    __shared__ float red[8][64][19];
    int tile = blockIdx.x, b = blockIdx.y;
    int t = threadIdx.x;
    int px = t & 63;
    int cpart = __builtin_amdgcn_readfirstlane(t >> 6);  // force SGPR
    int pxf = tile * 64 + px;
    int h = pxf / 96, w = pxf - h * 96;
    const char* xb = (const char*)(xt + (size_t)b * HW * 256);

    float acc[18];
#pragma unroll
    for (int o = 0; o < 18; ++o) acc[o] = 0.f;

    for (int tap = 0; tap < 9; ++tap) {
        int dy = tap / 3 - 1, dx = tap - (tap / 3) * 3 - 1;
        int h2 = h + dy, w2 = w + dx;
        bool ok = ((unsigned)h2 < 96u) && ((unsigned)w2 < 96u);
        int src = ok ? h2 * 96 + w2 : 0;
        const char* xp = xb + (size_t)src * 512;
#pragma unroll
        for (int mi = 0; mi < 4; ++mi) {
            int mm = cpart * 4 + mi;
            uint4 raw = *(const uint4*)(xp + mm * 16);
            const f16* hx = (const f16*)&raw;
            float xv[8];
#pragma unroll
            for (int e = 0; e < 8; ++e) xv[e] = ok ? (float)hx[e] : 0.f;
            const float* wb = w_offp + mm * 8;
#pragma unroll
            for (int o = 0; o < 18; ++o) {
                const float* wp = wb + (o * 9 + tap) * 256;   // SGPR-uniform
#pragma unroll
                for (int e = 0; e < 8; ++e) acc[o] += wp[e] * xv[e];
            }
        }
    }
#pragma unroll
    for (int o = 0; o < 18; ++o) red[cpart][px][o] = acc[o];
    __syncthreads();
    if (t < 64) {
        float s[18];
#pragma unroll
        for (int o = 0; o < 18; ++o) s[o] = b_off[o];
        for (int cp = 0; cp < 8; ++cp)
#pragma unroll
            for (int o = 0; o < 18; ++o) s[o] += red[cp][t][o];
#pragma unroll
        for (int o = 0; o < 18; ++o)
            off[((size_t)(b * 18 + o)) * HW + tile * 64 + t] = (f16)s[o];
    }
}

// ---------------- K2: deformable conv, fp16 MFMA, coalesced sampling ----------------
// 512 thr = 8 waves, one 64px x 256cout tile per block. y written NHWC f16.
// LDS 50KB, ~68 VGPR -> 3 blocks/CU: whole 576-block grid co-resident.
__global__ __launch_bounds__(512, 6) void k_dcn(const f16* __restrict__ xt,
                                                const f16* __restrict__ off,
                                                const f16* __restrict__ wt2,
                                                const float* __restrict__ b_dcn,
                                                f16* __restrict__ y,
                                                float* __restrict__ gsum,
                                                float* __restrict__ gss) {
    __shared__ uint4  A4[2048];     // 32KB  A[64px][256cin] f16, frag-permuted + XOR swz
    __shared__ int4   idx4[576];    // [tap][px] corner BYTE offsets
    __shared__ float4 wt4[576];     // [tap][px] bilinear weights

    int bx = blockIdx.x;
    int tile = bx % 144;
    int b = bx / 144;
    int pxb = tile * 64;
    int t = threadIdx.x;
    int lane = t & 63, wv = t >> 6;

    // ---- Phase A: bilinear tables ----
    for (int e = t; e < 576; e += 512) {
        int p = e & 63, tap = e >> 6;
        int pxf = pxb + p;
        int h = pxf / 96, w = pxf - h * 96;
        const f16* ob = off + (size_t)b * 18 * HW + pxf;
        float oy = (float)ob[(size_t)(2 * tap) * HW];
        float ox = (float)ob[(size_t)(2 * tap + 1) * HW];
        float py  = (float)(h + tap / 3 - 1) + oy;
        float pxx = (float)(w + tap % 3 - 1) + ox;
        float y0f = floorf(py), x0f = floorf(pxx);
        float wy = py - y0f, wx = pxx - x0f;
        int yi0 = (int)y0f, xi0 = (int)x0f;
        int yi1 = yi0 + 1, xi1 = xi0 + 1;
        bool vy0 = (unsigned)yi0 < 96u, vy1 = (unsigned)yi1 < 96u;
        bool vx0 = (unsigned)xi0 < 96u, vx1 = (unsigned)xi1 < 96u;
        int cy0 = min(max(yi0, 0), 95), cy1 = min(max(yi1, 0), 95);
        int cx0 = min(max(xi0, 0), 95), cx1 = min(max(xi1, 0), 95);
        idx4[e] = make_int4((cy0 * 96 + cx0) * 512, (cy0 * 96 + cx1) * 512,
                            (cy1 * 96 + cx0) * 512, (cy1 * 96 + cx1) * 512);
        wt4[e] = make_float4((vy0 && vx0) ? (1.f - wy) * (1.f - wx) : 0.f,
                             (vy0 && vx1) ? (1.f - wy) * wx : 0.f,
                             (vy1 && vx0) ? wy * (1.f - wx) : 0.f,
                             (vy1 && vx1) ? wy * wx : 0.f);
    }

    int g = lane >> 4, l15 = lane & 15;
    const char* xtb = (const char*)(xt + (size_t)b * HW * 256);

    f32x4 acc[4][2];
#pragma unroll
    for (int R = 0; R < 4; ++R) {
        acc[R][0] = (f32x4){0.f, 0.f, 0.f, 0.f};
        acc[R][1] = (f32x4){0.f, 0.f, 0.f, 0.f};
    }

    int m = lane & 31;              // cin chunk (16B)
    int phl = lane >> 5;            // pixel-pair member
    int qq = m & 3;
    int preA_base = (m >> 2) * 64 + (qq & 1) * 32 + ((qq & 2) ? 8 : 0);
    int cout0 = wv * 32 + l15;

    for (int tap = 0; tap < 9; ++tap) {
        __syncthreads();            // A4 free (covers Phase A on first iter)
        // ---- coalesced sampling: wave covers 8 px, 2 px per round ----
#pragma unroll
        for (int rr = 0; rr < 4; ++rr) {
            int p = wv * 8 + rr * 2 + phl;
            int4   id  = idx4[tap * 64 + p];
            float4 wgt = wt4[tap * 64 + p];
            uint4 q0 = *(const uint4*)(xtb + id.x + m * 16);
            uint4 q1 = *(const uint4*)(xtb + id.y + m * 16);
            uint4 q2 = *(const uint4*)(xtb + id.z + m * 16);
            uint4 q3 = *(const uint4*)(xtb + id.w + m * 16);
            const f16* a0 = (const f16*)&q0;
            const f16* a1 = (const f16*)&q1;
            const f16* a2 = (const f16*)&q2;
            const f16* a3 = (const f16*)&q3;
            union { f16 h[8]; uint2 u2[2]; } pu;
#pragma unroll
            for (int ii = 0; ii < 8; ++ii) {
                float s = wgt.x * (float)a0[ii] + wgt.y * (float)a1[ii]
                        + wgt.z * (float)a2[ii] + wgt.w * (float)a3[ii];
                pu.h[ii] = (f16)s;
            }
            int preA = p * 512 + preA_base;
            int swz = (p & 7) << 4;
            *(uint2*)((char*)A4 + ((preA) ^ swz))      = pu.u2[0];
            *(uint2*)((char*)A4 + ((preA + 16) ^ swz)) = pu.u2[1];
        }
        __syncthreads();

        // ---- MFMA: 8 K-steps of 32 ----
#pragma unroll
        for (int kb = 0; kb < 8; ++kb) {
            half8 Af[4];
#pragma unroll
            for (int R = 0; R < 4; ++R) {
                int byteA = ((R * 16 + l15) * 512 + kb * 64 + g * 16) ^ ((l15 & 7) << 4);
                Af[R] = *(const half8*)((const char*)A4 + byteA);
            }
#pragma unroll
            for (int nc = 0; nc < 2; ++nc) {
                const f16* bp = wt2 +
                    (((size_t)((tap * 8 + kb) * 4 + g) * 256 + cout0 + nc * 16) << 3);
                half8 Bf = *(const half8*)bp;
#pragma unroll
                for (int R = 0; R < 4; ++R)
                    acc[R][nc] = __builtin_amdgcn_mfma_f32_16x16x32_f16(Af[R], Bf, acc[R][nc], 0, 0, 0);
            }
        }
    }

    // ---- epilogue: bias, NHWC y via LDS transpose, groupnorm partials ----
    float bias0 = b_dcn[cout0], bias1 = b_dcn[cout0 + 16];
    float psum[2] = {0.f, 0.f}, pss[2] = {0.f, 0.f};
    __syncthreads();
    f16* ytile = (f16*)A4;          // [64 px][256 c]
#pragma unroll
    for (int R = 0; R < 4; ++R)
#pragma unroll
        for (int nc = 0; nc < 2; ++nc) {
            f32x4 v = acc[R][nc];
            float bb = nc ? bias1 : bias0;
            v.x += bb; v.y += bb; v.z += bb; v.w += bb;
            int cout = cout0 + nc * 16;
            int px0 = R * 16 + g * 4;
            ytile[(px0 + 0) * 256 + cout] = (f16)v.x;
            ytile[(px0 + 1) * 256 + cout] = (f16)v.y;
            ytile[(px0 + 2) * 256 + cout] = (f16)v.z;
            ytile[(px0 + 3) * 256 + cout] = (f16)v.w;
            psum[nc] += v.x + v.y + v.z + v.w;
            pss[nc]  += v.x * v.x + v.y * v.y + v.z * v.z + v.w * v.w;
        }
    __syncthreads();
    {
        const uint4* src = (const uint4*)A4;
        uint4* dst = (uint4*)(y + ((size_t)b * HW + pxb) * 256);
#pragma unroll
        for (int i = 0; i < 4; ++i)
            dst[i * 512 + t] = src[i * 512 + t];
    }
    __syncthreads();
    float4* red = (float4*)A4;      // ytile flushed, safe to reuse
    red[t] = make_float4(psum[0], pss[0], psum[1], pss[1]);
    __syncthreads();
    if (t < 32) {
        int wv2 = t >> 2, nc = (t >> 1) & 1, h8 = t & 1;
        float s = 0.f, ss = 0.f;
        for (int g2 = 0; g2 < 4; ++g2)
#pragma unroll
            for (int i = 0; i < 8; ++i) {
                float4 r = red[wv2 * 64 + g2 * 16 + h8 * 8 + i];
                s  += nc ? r.z : r.x;
                ss += nc ? r.w : r.y;
            }
        gsum[((size_t)(b * 32 + t)) * 144 + tile] = s;
        gss [((size_t)(b * 32 + t)) * 144 + tile] = ss;
    }
}

// ---------------- K3: groupnorm stats -> ab, plus folded sig-conv weights ----------------
__global__ void k_stats(const float* __restrict__ gsum, const float* __restrict__ gss,
                        const float* __restrict__ gamma, const float* __restrict__ beta,
                        const float* __restrict__ w2,
                        F2* __restrict__ ab, float* __restrict__ w2s) {
    int t = blockIdx.x * 256 + threadIdx.x;
    if (t >= 1024) return;
    int b = t >> 8, c = t & 255, g = c >> 3;
    const float* ps = gsum + (size_t)(b * 32 + g) * 144;
    const float* pq = gss  + (size_t)(b * 32 + g) * 144;
    float s = 0.f, q = 0.f;
    for (int i = 0; i < 144; ++i) { s += ps[i]; q += pq[i]; }
    const float inv_n = 1.f / 73728.f;
    float mu = s * inv_n;
    float var = q * inv_n - mu * mu;
    float rstd = rsqrtf(var + 1e-5f);
    float A = rstd * gamma[c];
    float Bv = beta[c] - mu * A;
    ab[t].a = A;
    ab[t].b = Bv;
#pragma unroll
    for (int tap = 0; tap < 9; ++tap)
        w2s[((size_t)(b * 9 + tap)) * 256 + c] = A * w2[c * 9 + tap];
}

// ---------------- K3b: cB[b][tap] = sum_c Bv_c * w2[c][tap] ----------------
__global__ void k_cb(const F2* __restrict__ ab, const float* __restrict__ w2,
                     float* __restrict__ cB) {
    int t = threadIdx.x;
    if (t >= 36) return;
    int b = t / 9, tap = t - (t / 9) * 9;
    float s = 0.f;
    for (int c = 0; c < 256; ++c) s += ab[b * 256 + c].b * w2[c * 9 + tap];
    cB[t] = s;
}

// ---------------- K4: sigmoid gate, coalesced NHWC reads ----------------
__global__ __launch_bounds__(256) void k_sig(const f16* __restrict__ y,
                                             const float* __restrict__ w2s,
                                             const float* __restrict__ cB,
                                             const float* __restrict__ b2,
                                             float* __restrict__ sig) {
    __shared__ float red[256][8];
    int tile = blockIdx.x, b = blockIdx.y;
    int t = threadIdx.x;
    int m = t & 31, sub = t >> 5;
    int pxb = tile * 64;
    const char* yb = (const char*)(y + (size_t)b * HW * 256);

    int hh[8], ww[8];
#pragma unroll
    for (int rr = 0; rr < 8; ++rr) {
        int pxf = pxb + rr * 8 + sub;
        hh[rr] = pxf / 96; ww[rr] = pxf - hh[rr] * 96;
    }
    float acc[8];
#pragma unroll
    for (int rr = 0; rr < 8; ++rr) acc[rr] = 0.f;

    for (int tap = 0; tap < 9; ++tap) {
        int dy = tap / 3 - 1, dx = tap - (tap / 3) * 3 - 1;
        const float* wp = w2s + ((size_t)(b * 9 + tap)) * 256 + m * 8;
        float wv0[8];
#pragma unroll
        for (int e = 0; e < 8; ++e) wv0[e] = wp[e];
        float cBt = cB[b * 9 + tap];
#pragma unroll
        for (int rr = 0; rr < 8; ++rr) {
            int h2 = hh[rr] + dy, w2i = ww[rr] + dx;
            bool ok = ((unsigned)h2 < 96u) && ((unsigned)w2i < 96u);
            int src = ok ? h2 * 96 + w2i : 0;
            uint4 raw = *(const uint4*)(yb + (size_t)src * 512 + m * 16);
            const f16* hx = (const f16*)&raw;
            float s = 0.f;
#pragma unroll
            for (int e = 0; e < 8; ++e) s += (float)hx[e] * wv0[e];
            s = ok ? s : 0.f;
            if (m == 0 && ok) s += cBt;
            acc[rr] += s;
        }
    }
#pragma unroll
    for (int rr = 0; rr < 8; ++rr) red[t][rr] = acc[rr];
    __syncthreads();
    if (t < 64) {
        int rr = t >> 3, sub2 = t & 7;
        float s = b2[0];
        for (int mm = 0; mm < 32; ++mm) s += red[sub2 * 32 + mm][rr];
        sig[(size_t)b * HW + pxb + rr * 8 + sub2] = 1.f / (1.f + expf(-s));
    }
}

// ---------------- K5: out = (y*A+B) * sig, NHWC->NCHW via LDS ----------------
// LDS stride 256 (r4 had 255: write collision bug). 64KB static LDS.
__global__ __launch_bounds__(256) void k_final(const f16* __restrict__ y,
                                               const F2* __restrict__ ab,
                                               const float* __restrict__ sig,
                                               float* __restrict__ out) {
    __shared__ float tile_s[64 * 256];
    int bx = blockIdx.x;
    int tile = bx % 144, b = bx / 144;
    int pxb = tile * 64;
    int t = threadIdx.x;
    int m = t & 31, sub = t >> 5;
    const char* yb = (const char*)(y + ((size_t)b * HW + pxb) * 256);
    float A[8], Bv[8];
    const F2* abp = ab + b * 256 + m * 8;
#pragma unroll
    for (int e = 0; e < 8; ++e) { A[e] = abp[e].a; Bv[e] = abp[e].b; }
#pragma unroll
    for (int rr = 0; rr < 8; ++rr) {
        int px = rr * 8 + sub;
        float sv = sig[(size_t)b * HW + pxb + px];
        uint4 raw = *(const uint4*)(yb + (size_t)px * 512 + m * 16);
        const f16* hx = (const f16*)&raw;
#pragma unroll
        for (int e = 0; e < 8; ++e)
            tile_s[px * 256 + m * 8 + e] = ((float)hx[e] * A[e] + Bv[e]) * sv;
    }
    __syncthreads();
#pragma unroll
    for (int r = 0; r < 16; ++r) {
        int c = r * 16 + (t >> 4);
        int q = t & 15;
        float4 v;
        v.x = tile_s[(q * 4 + 0) * 256 + c];
        v.y = tile_s[(q * 4 + 1) * 256 + c];
        v.z = tile_s[(q * 4 + 2) * 256 + c];
        v.w = tile_s[(q * 4 + 3) * 256 + c];
        *(float4*)(out + ((size_t)(b * 256 + c)) * HW + pxb + q * 4) = v;
    }
}

extern "C" void kernel_launch(void* const* d_in, const int* in_sizes, int n_in,
                              void* d_out, int out_size, void* d_ws, size_t ws_size,
                              hipStream_t stream) {
    (void)in_sizes; (void)n_in; (void)out_size; (void)ws_size;
    const float* x     = (const float*)d_in[0];
    const float* w_off = (const float*)d_in[1];
    const float* b_off = (const float*)d_in[2];
    const float* w_dcn = (const float*)d_in[3];
    const float* b_dcn = (const float*)d_in[4];
    const float* gamma = (const float*)d_in[5];
    const float* beta  = (const float*)d_in[6];
    const float* w2    = (const float*)d_in[7];
    const float* b2    = (const float*)d_in[8];
    float* out = (float*)d_out;

    char* p = (char*)d_ws;
    f16*   offp = (f16*)p;                        // 1,327,104
    f16*   y    = (f16*)(p + 1327104);            // 18,874,368  (NHWC)
    F2*    ab   = (F2*)(p + 20201472);            // 8,192
    char*  xtp  = p + 20209664;                   // 18,874,368
    f16*   xt   = (f16*)xtp;
    f16*   wt2  = (f16*)(p + 39084032);           // 1,179,648
    char*  wop  = p + 40263680;                   // 165,888
    float* w_offp = (float*)wop;
    // aliases (lifetime-disjoint, stream-serialized):
    float* gsum = (float*)wop;                    // after k_off done
    float* gss  = (float*)(wop + 73728);
    float* w2s  = (float*)xtp;                    // after k_dcn done
    float* cB   = (float*)(xtp + 36864);
    float* sig  = (float*)(xtp + 65536);
    // total footprint = 40,429,568 B (< 40,558,592 proven in r3)

    k_prep_x <<<576,  256, 0, stream>>>(x, xt);
    k_prep_w <<<2304, 256, 0, stream>>>(w_dcn, wt2);
    k_prep_wo<<<162,  256, 0, stream>>>(w_off, w_offp);
    k_off    <<<dim3(144, 4), 512, 0, stream>>>(xt, w_offp, b_off, offp);
    k_dcn    <<<576,  512, 0, stream>>>(xt, offp, wt2, b_dcn, y, gsum, gss);
    k_stats  <<<4,    256, 0, stream>>>(gsum, gss, gamma, beta, w2, ab, w2s);
    k_cb     <<<1,     64, 0, stream>>>(ab, w2, cB);
    k_sig    <<<dim3(144, 4), 256, 0, stream>>>(y, w2s, cB, b2, sig);
    k_final  <<<576,  256, 0, stream>>>(y, ab, sig, out);
}

// Round 9
// 499.440 us; speedup vs baseline: 4.7139x; 1.0591x over previous
//
#include <hip/hip_runtime.h>
#include <math.h>

#define HW 9216
#define CIN 256
#define COUT 256

typedef _Float16 f16;
typedef _Float16 half8 __attribute__((ext_vector_type(8)));
typedef float f32x4 __attribute__((ext_vector_type(4)));

struct F2 { float a, b; };

// XCD-locality swizzle (8 XCDs, blockIdx round-robins XCDs via bx&7):
// xcd = b*2 + (tile>=72)  ->  per-XCD working set = half a batch image
// (xt half = 2.4MB + wt2 1.2MB < 4MB L2). Whole chain uses the same map so
// producer L2 lines are still hot for the consumer.
__device__ __forceinline__ void swz576(int bx, int& b, int& tile) {
    int xcd = bx & 7, k = bx >> 3;      // k in [0,72)
    b = xcd >> 1;
    tile = (xcd & 1) * 72 + k;
}

// ---------------- K0a: x NCHW f32 -> xt NHWC f16 ----------------
__global__ __launch_bounds__(256) void k_prep_x(const float* __restrict__ x,
                                                f16* __restrict__ xt) {
    __shared__ f16 tile[64][256];
    int b, tl; swz576(blockIdx.x, b, tl);
    int pxb = tl * 64;
    int t = threadIdx.x;
    int cq = t >> 2, q = t & 3;
    for (int cp = 0; cp < 4; ++cp) {
        int c = cp * 64 + cq;
        const float* src = x + ((size_t)(b * 256 + c)) * HW + pxb + q * 16;
#pragma unroll
        for (int ii = 0; ii < 4; ++ii) {
            float4 v = *(const float4*)(src + ii * 4);
            int p0 = q * 16 + ii * 4;
            tile[p0 + 0][c] = (f16)v.x; tile[p0 + 1][c] = (f16)v.y;
            tile[p0 + 2][c] = (f16)v.z; tile[p0 + 3][c] = (f16)v.w;
        }
    }
    __syncthreads();
    int cg = t & 31, ph = t >> 5;
#pragma unroll
    for (int it = 0; it < 8; ++it) {
        int px = it * 8 + ph;
        *(uint4*)(xt + ((size_t)(b * HW + pxb + px)) * 256 + cg * 8) =
            *(const uint4*)&tile[px][cg * 8];
    }
}

// ---------------- K0b: w_dcn -> wt2 f16, frag-major (proven r6) ----------------
__global__ __launch_bounds__(256) void k_prep_w(const float* __restrict__ w_dcn,
                                                f16* __restrict__ wt2) {
    int gid = blockIdx.x * 256 + threadIdx.x;   // < 589824
    int e = gid & 7;
    int cout = (gid >> 3) & 255;
    int r2 = gid >> 11;
    int g = r2 & 3, kb = (r2 >> 2) & 7, tap = r2 >> 5;
    int cin = kb * 32 + ((e >> 2) << 4) + (g << 2) + (e & 3);
    wt2[gid] = (f16)w_dcn[((size_t)cout * 256 + cin) * 9 + tap];
}

// ---------------- K0c: w_off -> w_offp [(o*9+tap)*256 + cin] f32 ----------------
__global__ __launch_bounds__(256) void k_prep_wo(const float* __restrict__ w_off,
                                                 float* __restrict__ w_offp) {
    int gid = blockIdx.x * 256 + threadIdx.x;   // 41472 exact
    int cin = gid & 255;
    int r = gid >> 8;                           // o*9+tap
    int tap = r % 9, o = r / 9;
    w_offp[gid] = w_off[((size_t)o * 256 + cin) * 9 + tap];
}

// ---------------- K1: offsets conv 256->18, reads xt NHWC f16 ----------------
__global__ __launch_bounds__(512) void k_off(const f16* __restrict__ xt,
                                             const float* __restrict__ w_offp,
                                             const float* __restrict__ b_off,
                                             f16* __restrict__ off) {
    __shared__ float red[8][64][19];
    int b, tl; swz576(blockIdx.x, b, tl);
    int t = threadIdx.x;
    int px = t & 63;
    int cpart = __builtin_amdgcn_readfirstlane(t >> 6);  // force SGPR
    int pxf = tl * 64 + px;
    int h = pxf / 96, w = pxf - h * 96;
    const char* xb = (const char*)(xt + (size_t)b * HW * 256);

    float acc[18];
#pragma unroll
    for (int o = 0; o < 18; ++o) acc[o] = 0.f;

    for (int tap = 0; tap < 9; ++tap) {
        int dy = tap / 3 - 1, dx = tap - (tap / 3) * 3 - 1;
        int h2 = h + dy, w2 = w + dx;
        bool ok = ((unsigned)h2 < 96u) && ((unsigned)w2 < 96u);
        int src = ok ? h2 * 96 + w2 : 0;
        const char* xp = xb + (size_t)src * 512;
#pragma unroll
        for (int mi = 0; mi < 4; ++mi) {
            int mm = cpart * 4 + mi;
            uint4 raw = *(const uint4*)(xp + mm * 16);
            const f16* hx = (const f16*)&raw;
            float xv[8];
#pragma unroll
            for (int e = 0; e < 8; ++e) xv[e] = ok ? (float)hx[e] : 0.f;
            const float* wb = w_offp + mm * 8;
#pragma unroll
            for (int o = 0; o < 18; ++o) {
                const float* wp = wb + (o * 9 + tap) * 256;   // SGPR-uniform
#pragma unroll
                for (int e = 0; e < 8; ++e) acc[o] += wp[e] * xv[e];
            }
        }
    }
#pragma unroll
    for (int o = 0; o < 18; ++o) red[cpart][px][o] = acc[o];
    __syncthreads();
    if (t < 64) {
        float s[18];
#pragma unroll
        for (int o = 0; o < 18; ++o) s[o] = b_off[o];
        for (int cp = 0; cp < 8; ++cp)
#pragma unroll
            for (int o = 0; o < 18; ++o) s[o] += red[cp][t][o];
#pragma unroll
        for (int o = 0; o < 18; ++o)
            off[((size_t)(b * 18 + o)) * HW + tl * 64 + t] = (f16)s[o];
    }
}

// ---------------- K2: deformable conv, fp16 MFMA (r6 body + swizzle) ----------------
__global__ __launch_bounds__(512, 6) void k_dcn(const f16* __restrict__ xt,
                                                const f16* __restrict__ off,
                                                const f16* __restrict__ wt2,
                                                const float* __restrict__ b_dcn,
                                                f16* __restrict__ y,
                                                float* __restrict__ gsum,
                                                float* __restrict__ gss) {
    __shared__ uint4  A4[2048];     // 32KB  A[64px][256cin] f16, frag-permuted + XOR swz
    __shared__ int4   idx4[576];    // [tap][px] corner BYTE offsets
    __shared__ float4 wt4[576];     // [tap][px] bilinear weights

    int b, tile; swz576(blockIdx.x, b, tile);
    int pxb = tile * 64;
    int t = threadIdx.x;
    int lane = t & 63, wv = t >> 6;

    // ---- Phase A: bilinear tables ----
    for (int e = t; e < 576; e += 512) {
        int p = e & 63, tap = e >> 6;
        int pxf = pxb + p;
        int h = pxf / 96, w = pxf - h * 96;
        const f16* ob = off + (size_t)b * 18 * HW + pxf;
        float oy = (float)ob[(size_t)(2 * tap) * HW];
        float ox = (float)ob[(size_t)(2 * tap + 1) * HW];
        float py  = (float)(h + tap / 3 - 1) + oy;
        float pxx = (float)(w + tap % 3 - 1) + ox;
        float y0f = floorf(py), x0f = floorf(pxx);
        float wy = py - y0f, wx = pxx - x0f;
        int yi0 = (int)y0f, xi0 = (int)x0f;
        int yi1 = yi0 + 1, xi1 = xi0 + 1;
        bool vy0 = (unsigned)yi0 < 96u, vy1 = (unsigned)yi1 < 96u;
        bool vx0 = (unsigned)xi0 < 96u, vx1 = (unsigned)xi1 < 96u;
        int cy0 = min(max(yi0, 0), 95), cy1 = min(max(yi1, 0), 95);
        int cx0 = min(max(xi0, 0), 95), cx1 = min(max(xi1, 0), 95);
        idx4[e] = make_int4((cy0 * 96 + cx0) * 512, (cy0 * 96 + cx1) * 512,
                            (cy1 * 96 + cx0) * 512, (cy1 * 96 + cx1) * 512);
        wt4[e] = make_float4((vy0 && vx0) ? (1.f - wy) * (1.f - wx) : 0.f,
                             (vy0 && vx1) ? (1.f - wy) * wx : 0.f,
                             (vy1 && vx0) ? wy * (1.f - wx) : 0.f,
                             (vy1 && vx1) ? wy * wx : 0.f);
    }

    int g = lane >> 4, l15 = lane & 15;
    const char* xtb = (const char*)(xt + (size_t)b * HW * 256);

    f32x4 acc[4][2];
#pragma unroll
    for (int R = 0; R < 4; ++R) {
        acc[R][0] = (f32x4){0.f, 0.f, 0.f, 0.f};
        acc[R][1] = (f32x4){0.f, 0.f, 0.f, 0.f};
    }

    int m = lane & 31;              // cin chunk (16B)
    int phl = lane >> 5;            // pixel-pair member
    int qq = m & 3;
    int preA_base = (m >> 2) * 64 + (qq & 1) * 32 + ((qq & 2) ? 8 : 0);
    int cout0 = wv * 32 + l15;

    for (int tap = 0; tap < 9; ++tap) {
        __syncthreads();            // A4 free (covers Phase A on first iter)
#pragma unroll
        for (int rr = 0; rr < 4; ++rr) {
            int p = wv * 8 + rr * 2 + phl;
            int4   id  = idx4[tap * 64 + p];
            float4 wgt = wt4[tap * 64 + p];
            uint4 q0 = *(const uint4*)(xtb + id.x + m * 16);
            uint4 q1 = *(const uint4*)(xtb + id.y + m * 16);
            uint4 q2 = *(const uint4*)(xtb + id.z + m * 16);
            uint4 q3 = *(const uint4*)(xtb + id.w + m * 16);
            const f16* a0 = (const f16*)&q0;
            const f16* a1 = (const f16*)&q1;
            const f16* a2 = (const f16*)&q2;
            const f16* a3 = (const f16*)&q3;
            union { f16 h[8]; uint2 u2[2]; } pu;
#pragma unroll
            for (int ii = 0; ii < 8; ++ii) {
                float s = wgt.x * (float)a0[ii] + wgt.y * (float)a1[ii]
                        + wgt.z * (float)a2[ii] + wgt.w * (float)a3[ii];
                pu.h[ii] = (f16)s;
            }
            int preA = p * 512 + preA_base;
            int swz = (p & 7) << 4;
            *(uint2*)((char*)A4 + ((preA) ^ swz))      = pu.u2[0];
            *(uint2*)((char*)A4 + ((preA + 16) ^ swz)) = pu.u2[1];
        }
        __syncthreads();

#pragma unroll
        for (int kb = 0; kb < 8; ++kb) {
            half8 Af[4];
#pragma unroll
            for (int R = 0; R < 4; ++R) {
                int byteA = ((R * 16 + l15) * 512 + kb * 64 + g * 16) ^ ((l15 & 7) << 4);
                Af[R] = *(const half8*)((const char*)A4 + byteA);
            }
#pragma unroll
            for (int nc = 0; nc < 2; ++nc) {
                const f16* bp = wt2 +
                    (((size_t)((tap * 8 + kb) * 4 + g) * 256 + cout0 + nc * 16) << 3);
                half8 Bf = *(const half8*)bp;
#pragma unroll
                for (int R = 0; R < 4; ++R)
                    acc[R][nc] = __builtin_amdgcn_mfma_f32_16x16x32_f16(Af[R], Bf, acc[R][nc], 0, 0, 0);
            }
        }
    }

    // ---- epilogue ----
    float bias0 = b_dcn[cout0], bias1 = b_dcn[cout0 + 16];
    float psum[2] = {0.f, 0.f}, pss[2] = {0.f, 0.f};
    __syncthreads();
    f16* ytile = (f16*)A4;          // [64 px][256 c]
#pragma unroll
    for (int R = 0; R < 4; ++R)
#pragma unroll
        for (int nc = 0; nc < 2; ++nc) {
            f32x4 v = acc[R][nc];
            float bb = nc ? bias1 : bias0;
            v.x += bb; v.y += bb; v.z += bb; v.w += bb;
            int cout = cout0 + nc * 16;
            int px0 = R * 16 + g * 4;
            ytile[(px0 + 0) * 256 + cout] = (f16)v.x;
            ytile[(px0 + 1) * 256 + cout] = (f16)v.y;
            ytile[(px0 + 2) * 256 + cout] = (f16)v.z;
            ytile[(px0 + 3) * 256 + cout] = (f16)v.w;
            psum[nc] += v.x + v.y + v.z + v.w;
            pss[nc]  += v.x * v.x + v.y * v.y + v.z * v.z + v.w * v.w;
        }
    __syncthreads();
    {
        const uint4* src = (const uint4*)A4;
        uint4* dst = (uint4*)(y + ((size_t)b * HW + pxb) * 256);
#pragma unroll
        for (int i = 0; i < 4; ++i)
            dst[i * 512 + t] = src[i * 512 + t];
    }
    __syncthreads();
    float4* red = (float4*)A4;
    red[t] = make_float4(psum[0], pss[0], psum[1], pss[1]);
    __syncthreads();
    if (t < 32) {
        float s = 0.f, ss = 0.f;
        int wv2 = t >> 2, nc = (t >> 1) & 1, h8 = t & 1;
        for (int g2 = 0; g2 < 4; ++g2)
#pragma unroll
            for (int i = 0; i < 8; ++i) {
                float4 r = red[wv2 * 64 + g2 * 16 + h8 * 8 + i];
                s  += nc ? r.z : r.x;
                ss += nc ? r.w : r.y;
            }
        gsum[((size_t)(b * 32 + t)) * 144 + tile] = s;
        gss [((size_t)(b * 32 + t)) * 144 + tile] = ss;
    }
}

// ---------------- K3: groupnorm stats -> ab + folded sig-conv weights ----------------
__global__ void k_stats(const float* __restrict__ gsum, const float* __restrict__ gss,
                        const float* __restrict__ gamma, const float* __restrict__ beta,
                        const float* __restrict__ w2,
                        F2* __restrict__ ab, float* __restrict__ w2s) {
    int t = blockIdx.x * 256 + threadIdx.x;
    if (t >= 1024) return;
    int b = t >> 8, c = t & 255, g = c >> 3;
    const float* ps = gsum + (size_t)(b * 32 + g) * 144;
    const float* pq = gss  + (size_t)(b * 32 + g) * 144;
    float s = 0.f, q = 0.f;
    for (int i = 0; i < 144; ++i) { s += ps[i]; q += pq[i]; }
    const float inv_n = 1.f / 73728.f;
    float mu = s * inv_n;
    float var = q * inv_n - mu * mu;
    float rstd = rsqrtf(var + 1e-5f);
    float A = rstd * gamma[c];
    float Bv = beta[c] - mu * A;
    ab[t].a = A;
    ab[t].b = Bv;
#pragma unroll
    for (int tap = 0; tap < 9; ++tap)
        w2s[((size_t)(b * 9 + tap)) * 256 + c] = A * w2[c * 9 + tap];
}

// ---------------- K3b: cB[b][tap] = sum_c Bv_c * w2[c][tap] ----------------
__global__ void k_cb(const F2* __restrict__ ab, const float* __restrict__ w2,
                     float* __restrict__ cB) {
    int t = threadIdx.x;
    if (t >= 36) return;
    int b = t / 9, tap = t - (t / 9) * 9;
    float s = 0.f;
    for (int c = 0; c < 256; ++c) s += ab[b * 256 + c].b * w2[c * 9 + tap];
    cB[t] = s;
}

// ---------------- K4: sigmoid gate, 32-px blocks (2x occupancy) + swizzle ----------------
__global__ __launch_bounds__(256) void k_sig(const f16* __restrict__ y,
                                             const float* __restrict__ w2s,
                                             const float* __restrict__ cB,
                                             const float* __restrict__ b2,
                                             float* __restrict__ sig) {
    __shared__ float red[256][4];
    int bx = blockIdx.x;                  // 1152 blocks
    int xcd = bx & 7, kk = bx >> 3;       // kk in [0,144)
    int b = xcd >> 1;
    int tile = (xcd & 1) * 72 + (kk >> 1);
    int pxb = tile * 64 + (kk & 1) * 32;
    int t = threadIdx.x;
    int m = t & 31, sub = t >> 5;
    const char* yb = (const char*)(y + (size_t)b * HW * 256);

    int hh[4], ww[4];
#pragma unroll
    for (int rr = 0; rr < 4; ++rr) {
        int pxf = pxb + rr * 8 + sub;
        hh[rr] = pxf / 96; ww[rr] = pxf - hh[rr] * 96;
    }
    float acc[4];
#pragma unroll
    for (int rr = 0; rr < 4; ++rr) acc[rr] = 0.f;

    for (int tap = 0; tap < 9; ++tap) {
        int dy = tap / 3 - 1, dx = tap - (tap / 3) * 3 - 1;
        const float* wp = w2s + ((size_t)(b * 9 + tap)) * 256 + m * 8;
        float wv0[8];
#pragma unroll
        for (int e = 0; e < 8; ++e) wv0[e] = wp[e];
        float cBt = cB[b * 9 + tap];
#pragma unroll
        for (int rr = 0; rr < 4; ++rr) {
            int h2 = hh[rr] + dy, w2i = ww[rr] + dx;
            bool ok = ((unsigned)h2 < 96u) && ((unsigned)w2i < 96u);
            int src = ok ? h2 * 96 + w2i : 0;
            uint4 raw = *(const uint4*)(yb + (size_t)src * 512 + m * 16);
            const f16* hx = (const f16*)&raw;
            float s = 0.f;
#pragma unroll
            for (int e = 0; e < 8; ++e) s += (float)hx[e] * wv0[e];
            s = ok ? s : 0.f;
            if (m == 0 && ok) s += cBt;
            acc[rr] += s;
        }
    }
#pragma unroll
    for (int rr = 0; rr < 4; ++rr) red[t][rr] = acc[rr];
    __syncthreads();
    if (t < 32) {
        int rr = t >> 3, sub2 = t & 7;
        float s = b2[0];
        for (int mm = 0; mm < 32; ++mm) s += red[sub2 * 32 + mm][rr];
        sig[(size_t)b * HW + pxb + rr * 8 + sub2] = 1.f / (1.f + expf(-s));
    }
}

// ---------------- K5: out = (y*A+B) * sig, NHWC->NCHW via LDS ----------------
__global__ __launch_bounds__(256) void k_final(const f16* __restrict__ y,
                                               const F2* __restrict__ ab,
                                               const float* __restrict__ sig,
                                               float* __restrict__ out) {
    __shared__ float tile_s[64 * 256];
    int b, tl; swz576(blockIdx.x, b, tl);
    int pxb = tl * 64;
    int t = threadIdx.x;
    int m = t & 31, sub = t >> 5;
    const char* yb = (const char*)(y + ((size_t)b * HW + pxb) * 256);
    float A[8], Bv[8];
    const F2* abp = ab + b * 256 + m * 8;
#pragma unroll
    for (int e = 0; e < 8; ++e) { A[e] = abp[e].a; Bv[e] = abp[e].b; }
#pragma unroll
    for (int rr = 0; rr < 8; ++rr) {
        int px = rr * 8 + sub;
        float sv = sig[(size_t)b * HW + pxb + px];
        uint4 raw = *(const uint4*)(yb + (size_t)px * 512 + m * 16);
        const f16* hx = (const f16*)&raw;
#pragma unroll
        for (int e = 0; e < 8; ++e)
            tile_s[px * 256 + m * 8 + e] = ((float)hx[e] * A[e] + Bv[e]) * sv;
    }
    __syncthreads();
#pragma unroll
    for (int r = 0; r < 16; ++r) {
        int c = r * 16 + (t >> 4);
        int q = t & 15;
        float4 v;
        v.x = tile_s[(q * 4 + 0) * 256 + c];
        v.y = tile_s[(q * 4 + 1) * 256 + c];
        v.z = tile_s[(q * 4 + 2) * 256 + c];
        v.w = tile_s[(q * 4 + 3) * 256 + c];
        *(float4*)(out + ((size_t)(b * 256 + c)) * HW + pxb + q * 4) = v;
    }
}

extern "C" void kernel_launch(void* const* d_in, const int* in_sizes, int n_in,
                              void* d_out, int out_size, void* d_ws, size_t ws_size,
                              hipStream_t stream) {
    (void)in_sizes; (void)n_in; (void)out_size; (void)ws_size;
    const float* x     = (const float*)d_in[0];
    const float* w_off = (const float*)d_in[1];
    const float* b_off = (const float*)d_in[2];
    const float* w_dcn = (const float*)d_in[3];
    const float* b_dcn = (const float*)d_in[4];
    const float* gamma = (const float*)d_in[5];
    const float* beta  = (const float*)d_in[6];
    const float* w2    = (const float*)d_in[7];
    const float* b2    = (const float*)d_in[8];
    float* out = (float*)d_out;

    char* p = (char*)d_ws;
    f16*   offp = (f16*)p;                        // 1,327,104
    f16*   y    = (f16*)(p + 1327104);            // 18,874,368  (NHWC)
    F2*    ab   = (F2*)(p + 20201472);            // 8,192
    char*  xtp  = p + 20209664;                   // 18,874,368
    f16*   xt   = (f16*)xtp;
    f16*   wt2  = (f16*)(p + 39084032);           // 1,179,648
    char*  wop  = p + 40263680;                   // 165,888
    float* w_offp = (float*)wop;
    // aliases (lifetime-disjoint, stream-serialized):
    float* gsum = (float*)wop;                    // after k_off done
    float* gss  = (float*)(wop + 73728);
    float* w2s  = (float*)xtp;                    // after k_dcn done
    float* cB   = (float*)(xtp + 36864);
    float* sig  = (float*)(xtp + 65536);

    k_prep_x <<<576,  256, 0, stream>>>(x, xt);
    k_prep_w <<<2304, 256, 0, stream>>>(w_dcn, wt2);
    k_prep_wo<<<162,  256, 0, stream>>>(w_off, w_offp);
    k_off    <<<576,  512, 0, stream>>>(xt, w_offp, b_off, offp);
    k_dcn    <<<576,  512, 0, stream>>>(xt, offp, wt2, b_dcn, y, gsum, gss);
    k_stats  <<<4,    256, 0, stream>>>(gsum, gss, gamma, beta, w2, ab, w2s);
    k_cb     <<<1,     64, 0, stream>>>(ab, w2, cB);
    k_sig    <<<1152, 256, 0, stream>>>(y, w2s, cB, b2, sig);
    k_final  <<<576,  256, 0, stream>>>(y, ab, sig, out);
}